// Round 8
// baseline (175.792 us; speedup 1.0000x reference)
//
#include <hip/hip_runtime.h>
#include <hip/hip_bf16.h>
#include <cstddef>
#include <cstdint>

// GINConvFFT round 8: software-pipelined K-loops (multi-stage LDS, raw
// s_barrier + fine-grained manual s_waitcnt vmcnt(N)), XCD-aware swizzles,
// pure-bf16 gl2lds staging (x pre-cast in prep3).
//   prep3:  xb=bf16(x); MallC even slices; MT; Wt
//   zmsq:   blocks 0-511 (swizzled): Z[(b*64+o)][k*512+m] = Wt . xb^T
//           blocks 512-543: MallC odd slices = M_s^2
//   ysum:   Yh[ks][r][o] = half-K partial of MallC . Z^T   (512 blk, 3-stage)
//   bn_part/bn_final/bn_out: BN stats over Yh0+Yh1, normalize+relu+w2+b2.
#define B_   32
#define N_   512
#define D_   768
#define OUT_ 64
#define R_   (B_ * N_)

typedef unsigned short u16;
typedef __bf16 bf16x8 __attribute__((ext_vector_type(8)));
typedef float  f32x4  __attribute__((ext_vector_type(4)));
typedef unsigned short u16x8 __attribute__((ext_vector_type(8)));

#define WAITVM(n) __asm__ __volatile__("s_waitcnt vmcnt(" #n ")" ::: "memory")
#define SBAR()    __builtin_amdgcn_s_barrier()

__device__ __forceinline__ u16 f2bf(float f) {
    __hip_bfloat16 h = __float2bfloat16(f);
    return __builtin_bit_cast(u16, h);
}

__device__ __forceinline__ f32x4 mfma16(u16x8 a, u16x8 b, f32x4 c) {
    return __builtin_amdgcn_mfma_f32_16x16x32_bf16(
        __builtin_bit_cast(bf16x8, a), __builtin_bit_cast(bf16x8, b), c, 0, 0, 0);
}

// async global->LDS, 16B/lane; LDS dest = wave-uniform base + lane*16
__device__ __forceinline__ void gl2lds16(const void* g, void* l) {
    __builtin_amdgcn_global_load_lds(
        (const __attribute__((address_space(1))) unsigned int*)g,
        (__attribute__((address_space(3))) unsigned int*)l, 16, 0, 0);
}

// ---------------------------------------------------------------------------
// prep3: [0,6144) cast x->bf16 | [6144,6656) M even slices + MT | rest Wt
// ---------------------------------------------------------------------------
__global__ __launch_bounds__(256) void prep3(
    const float* __restrict__ x, const float* __restrict__ support,
    const float* __restrict__ weight, const float* __restrict__ epsp,
    u16* __restrict__ xb, u16* __restrict__ MallC, u16* __restrict__ MT,
    u16* __restrict__ Wt)
{
    const int blk = blockIdx.x, tid = threadIdx.x;
    __shared__ float t[32][33];
    if (blk < 6144) {
        int i = (blk * 256 + tid) * 8;
        f32x4 a = *(const f32x4*)(x + i);
        f32x4 b = *(const f32x4*)(x + i + 4);
        u16x8 o;
#pragma unroll
        for (int j = 0; j < 4; ++j) { o[j] = f2bf(a[j]); o[4 + j] = f2bf(b[j]); }
        *(u16x8*)(xb + i) = o;
    } else if (blk < 6656) {
        int local = blk - 6144;
        int s = local >> 8, rem = local & 255;
        int n0 = (rem >> 4) * 32, m0 = (rem & 15) * 32;
        const float f = 1.0f + epsp[0];
        const float* S = support + (size_t)s * 262144;
#pragma unroll
        for (int p = 0; p < 4; ++p) {
            int nl = p * 8 + (tid >> 5), ml = tid & 31;
            float v = S[(size_t)(n0 + nl) * 512 + m0 + ml];
            if (n0 + nl == m0 + ml) v += f;
            MallC[(size_t)(n0 + nl) * 2048 + s * 1024 + m0 + ml] = f2bf(v);
            t[nl][ml] = v;
        }
        __syncthreads();
#pragma unroll
        for (int p = 0; p < 4; ++p) {
            int ml = p * 8 + (tid >> 5), nl = tid & 31;
            MT[(size_t)s * 262144 + (size_t)(m0 + ml) * 512 + n0 + nl] = f2bf(t[nl][ml]);
        }
    } else {
        int idx = (blk - 6656) * 256 + tid;          // 4*64*768 = 196608
        int k = idx / 49152, rem = idx % 49152;
        int o = rem / 768, d = rem % 768;
        int l = d >> 6, hh = d & 63;
        Wt[idx] = f2bf(weight[((size_t)l * 256 + hh * 4 + k) * 64 + o]);
    }
}

// ---------------------------------------------------------------------------
// zmsq:
//  blocks 0-511 (swizzled so y-pairs share XCD): zgemm tile 128(Wt rows)x64(m)
//    BK=64, K=768, 12 iters, 2-stage pipeline (wait vmcnt(6)).
//  blocks 512-543: msq 128x128, K=512, BK=64 (single-buffered; concurrent).
// ---------------------------------------------------------------------------
__global__ __launch_bounds__(256) void zmsq(
    const u16* __restrict__ Wt, const u16* __restrict__ xb,
    const u16* __restrict__ MallC_in, const u16* __restrict__ MT,
    u16* __restrict__ Z, u16* __restrict__ MallC_out)
{
    __shared__ __align__(16) char smem[49152];
    u16* SM = (u16*)smem;
    const int tid = threadIdx.x, lane = tid & 63, wid = tid >> 6;
    const int wr = wid >> 1, wc = wid & 1;
    const int lrow = lane & 15, lk = (lane >> 4) * 8;
    const int q = lane >> 4;
    const int bid = blockIdx.x;

    if (bid < 512) {
        // swizzle: j=bid&7 (XCD), y=(bid>>3)&1, g=bid>>4 ; rt = g*8+j
        const int j = bid & 7, y = (bid >> 3) & 1, g = bid >> 4;
        const int rt = g * 8 + j;
        const int b = rt >> 3;

        // stage layout (u16): base s*12288; A: pan*4096 + sub*512 (16 KB);
        // B at +8192: pan*2048 + sub*512 (8 KB)
        const u16* gsrc[6]; int loff[6];
#pragma unroll
        for (int t = 0; t < 6; ++t) {
            int idx = wid * 6 + t;
            if (idx < 16) {
                int pan = idx >> 3, sub = idx & 7;
                gsrc[t] = Wt + (size_t)(y * 128 + sub * 16 + lrow) * 768 + pan * 32 + lk;
                loff[t] = pan * 4096 + sub * 512;
            } else {
                int i2 = idx - 16;
                int pan = i2 >> 2, sub = i2 & 3;
                gsrc[t] = xb + (size_t)(rt * 64 + sub * 16 + lrow) * 768 + pan * 32 + lk;
                loff[t] = 8192 + pan * 2048 + sub * 512;
            }
        }
        // preamble: stage 0
#pragma unroll
        for (int t = 0; t < 6; ++t) { gl2lds16(gsrc[t], SM + loff[t]); gsrc[t] += 64; }

        f32x4 acc[4][2] = {};
#pragma unroll
        for (int kk = 0; kk < 12; ++kk) {
            if (kk < 11) {
                u16* base = SM + ((kk + 1) & 1) * 12288;
#pragma unroll
                for (int t = 0; t < 6; ++t) { gl2lds16(gsrc[t], base + loff[t]); gsrc[t] += 64; }
                WAITVM(6);
            } else {
                WAITVM(0);
            }
            SBAR();
            const u16* base = SM + (kk & 1) * 12288;
#pragma unroll
            for (int pan = 0; pan < 2; ++pan) {
                u16x8 af[4], bq[2];
#pragma unroll
                for (int f = 0; f < 4; ++f)
                    af[f] = *(const u16x8*)(base + pan * 4096 + (wr * 4 + f) * 512 + lane * 8);
#pragma unroll
                for (int f = 0; f < 2; ++f)
                    bq[f] = *(const u16x8*)(base + 8192 + pan * 2048 + (wc * 2 + f) * 512 + lane * 8);
#pragma unroll
                for (int fi = 0; fi < 4; ++fi)
#pragma unroll
                    for (int fj = 0; fj < 2; ++fj)
                        acc[fi][fj] = mfma16(af[fi], bq[fj], acc[fi][fj]);
            }
            SBAR();
        }
        // epilogue: per-wave repack 64(o) x 32(m), stride 40 u16
        u16* Rw = (u16*)smem + wid * 2560;
#pragma unroll
        for (int fi = 0; fi < 4; ++fi)
#pragma unroll
            for (int fj = 0; fj < 2; ++fj)
#pragma unroll
                for (int r = 0; r < 4; ++r)
                    Rw[(fi * 16 + q * 4 + r) * 40 + fj * 16 + lrow] = f2bf(acc[fi][fj][r]);
        __syncthreads();
        const int k = y * 2 + wr;
        const int m0 = (rt & 7) * 64 + wc * 32;
#pragma unroll
        for (int p = 0; p < 4; ++p) {
            int row = p * 16 + (lane >> 2);          // o
            int cc = (lane & 3) * 8;
            u16x8 v = *(const u16x8*)(Rw + row * 40 + cc);
            *(u16x8*)(Z + (size_t)(b * 64 + row) * 2048 + k * 512 + m0 + cc) = v;
        }
    } else {
        // msq: 128x128, K=512, BK=64, single-buffered (32 blocks, concurrent)
        u16* St = SM;
        int lb = bid - 512;
        int s = lb >> 4, rem = lb & 15;
        int i0 = (rem >> 2) * 128, j0 = (rem & 3) * 128;
        const u16* Ab = MallC_in + s * 1024;         // stride 2048
        const u16* Bb = MT + (size_t)s * 262144;     // stride 512

        const u16* gsrc[8]; u16* ldst[8];
#pragma unroll
        for (int t = 0; t < 8; ++t) {
            int idx = wid * 8 + t;
            int pan = idx >> 4, q2 = idx & 15;
            if (q2 < 8) {
                gsrc[t] = Ab + (size_t)(i0 + q2 * 16 + lrow) * 2048 + pan * 32 + lk;
                ldst[t] = St + pan * 8192 + q2 * 512;
            } else {
                gsrc[t] = Bb + (size_t)(j0 + (q2 - 8) * 16 + lrow) * 512 + pan * 32 + lk;
                ldst[t] = St + pan * 8192 + 4096 + (q2 - 8) * 512;
            }
        }
        f32x4 acc[4][4] = {};
        for (int kk = 0; kk < 8; ++kk) {
#pragma unroll
            for (int t = 0; t < 8; ++t) gl2lds16(gsrc[t], ldst[t]);
#pragma unroll
            for (int t = 0; t < 8; ++t) gsrc[t] += 64;
            __syncthreads();
#pragma unroll
            for (int pan = 0; pan < 2; ++pan) {
                u16x8 af[4], bq[4];
#pragma unroll
                for (int f = 0; f < 4; ++f)
                    af[f] = *(const u16x8*)(St + pan * 8192 + (wr * 4 + f) * 512 + lane * 8);
#pragma unroll
                for (int f = 0; f < 4; ++f)
                    bq[f] = *(const u16x8*)(St + pan * 8192 + 4096 + (wc * 4 + f) * 512 + lane * 8);
#pragma unroll
                for (int fi = 0; fi < 4; ++fi)
#pragma unroll
                    for (int fj = 0; fj < 4; ++fj)
                        acc[fi][fj] = mfma16(af[fi], bq[fj], acc[fi][fj]);
            }
            __syncthreads();
        }
#pragma unroll
        for (int fi = 0; fi < 4; ++fi)
#pragma unroll
            for (int fj = 0; fj < 4; ++fj)
#pragma unroll
                for (int r = 0; r < 4; ++r) {
                    int n = i0 + wr * 64 + fi * 16 + q * 4 + r;
                    int c = j0 + wc * 64 + fj * 16 + lrow;
                    MallC_out[(size_t)n * 2048 + (2 * s + 1) * 512 + c] = f2bf(acc[fi][fj][r]);
                }
    }
}

// ---------------------------------------------------------------------------
// ysum: 512 blocks, XCD-swizzled so all 16 blocks of batch b share XCD b%8.
// Tile 64n x 64o, K=1024 (k half), BK=64, 16 iters, 3-stage pipeline
// (prefetch depth 2, wait vmcnt(8)).
// ---------------------------------------------------------------------------
__global__ __launch_bounds__(256) void ysum(
    const u16* __restrict__ MallC, const u16* __restrict__ Z,
    float* __restrict__ Yh)
{
    __shared__ __align__(16) u16 SM[24576];          // 3 stages x 8192 u16
    const int tid = threadIdx.x, lane = tid & 63, wid = tid >> 6;
    const int wr = wid >> 1, wc = wid & 1;
    const int lrow = lane & 15, lk = (lane >> 4) * 8;
    const int bid = blockIdx.x;
    // swizzle: xcd = bid&7; t = bid>>3; b = (t>>4)*8 + xcd; nt = (t>>1)&7; ks = t&1
    const int xcd = bid & 7, tt = bid >> 3;
    const int b = (tt >> 4) * 8 + xcd;
    const int nt = (tt >> 1) & 7, ks = tt & 1;
    const int n0 = nt * 64;
    const int r0 = b * 512 + n0;
    const size_t km0 = (size_t)ks * 1024;

    // stage layout (u16): base s*8192; A: pan*2048+sub*512; B at +4096 same
    const u16* gsrc[4]; int loff[4];
#pragma unroll
    for (int t = 0; t < 4; ++t) {
        int idx = wid * 4 + t;
        if (idx < 8) {
            int pan = idx >> 2, sub = idx & 3;
            gsrc[t] = MallC + (size_t)(n0 + sub * 16 + lrow) * 2048 + km0 + pan * 32 + lk;
            loff[t] = pan * 2048 + sub * 512;
        } else {
            int i2 = idx - 8;
            int pan = i2 >> 2, sub = i2 & 3;
            gsrc[t] = Z + (size_t)(b * 64 + sub * 16 + lrow) * 2048 + km0 + pan * 32 + lk;
            loff[t] = 4096 + pan * 2048 + sub * 512;
        }
    }
    // preamble: stages 0,1
#pragma unroll
    for (int st = 0; st < 2; ++st) {
#pragma unroll
        for (int t = 0; t < 4; ++t) { gl2lds16(gsrc[t], SM + st * 8192 + loff[t]); gsrc[t] += 64; }
    }
    f32x4 acc[2][2] = {};
#pragma unroll
    for (int kk = 0; kk < 16; ++kk) {
        int nxt = kk + 2;
        if (nxt < 16) {
            u16* base = SM + (nxt % 3) * 8192;
#pragma unroll
            for (int t = 0; t < 4; ++t) { gl2lds16(gsrc[t], base + loff[t]); gsrc[t] += 64; }
        }
        if (kk < 14) WAITVM(8);
        else if (kk == 14) WAITVM(4);
        else WAITVM(0);
        SBAR();
        const u16* base = SM + (kk % 3) * 8192;
#pragma unroll
        for (int pan = 0; pan < 2; ++pan) {
            u16x8 af[2], bq[2];
#pragma unroll
            for (int f = 0; f < 2; ++f)
                af[f] = *(const u16x8*)(base + pan * 2048 + (wr * 2 + f) * 512 + lane * 8);
#pragma unroll
            for (int f = 0; f < 2; ++f)
                bq[f] = *(const u16x8*)(base + 4096 + pan * 2048 + (wc * 2 + f) * 512 + lane * 8);
#pragma unroll
            for (int fi = 0; fi < 2; ++fi)
#pragma unroll
                for (int fj = 0; fj < 2; ++fj)
                    acc[fi][fj] = mfma16(af[fi], bq[fj], acc[fi][fj]);
        }
        SBAR();
    }
    const int q = lane >> 4;
    float* Yk = Yh + (size_t)ks * R_ * 64;
#pragma unroll
    for (int fi = 0; fi < 2; ++fi)
#pragma unroll
        for (int fj = 0; fj < 2; ++fj)
#pragma unroll
            for (int r = 0; r < 4; ++r) {
                int rr = r0 + wr * 32 + fi * 16 + q * 4 + r;
                int o  = wc * 32 + fj * 16 + lrow;
                Yk[(size_t)rr * 64 + o] = acc[fi][fj][r];
            }
}

// ---------------------------------------------------------------------------
// bn_part: grid 256, block j: rows j*64..+63, v = Yh0+Yh1, partial sum/sumsq.
// ---------------------------------------------------------------------------
__global__ __launch_bounds__(256) void bn_part(
    const float* __restrict__ Yh, float* __restrict__ part)
{
    const int blk = blockIdx.x, tid = threadIdx.x;
    const int o = tid & 63, g = tid >> 6;
    float s = 0.f, s2 = 0.f;
#pragma unroll
    for (int p = 0; p < 16; ++p) {
        int r = blk * 64 + p * 4 + g;
        size_t off = (size_t)r * 64 + o;
        float v = Yh[off] + Yh[(size_t)R_ * 64 + off];
        s += v; s2 += v * v;
    }
    __shared__ float ls[4][64], ls2[4][64];
    ls[g][o] = s; ls2[g][o] = s2;
    __syncthreads();
    if (tid < 64) {
        float t = 0.f, t2 = 0.f;
#pragma unroll
        for (int g2 = 0; g2 < 4; ++g2) { t += ls[g2][tid]; t2 += ls2[g2][tid]; }
        part[blk * 128 + tid]      = t;
        part[blk * 128 + 64 + tid] = t2;
    }
}

// bn_final: stats[o] = scale, stats[64+o] = shift
__global__ __launch_bounds__(256) void bn_final(
    const float* __restrict__ part, const float* __restrict__ gamma,
    const float* __restrict__ beta, float* __restrict__ stats)
{
    const int tid = threadIdx.x;
    const int c = tid & 63, g = tid >> 6;
    float s = 0.f, s2 = 0.f;
    for (int b = g; b < 256; b += 4) {
        s  += part[b * 128 + c];
        s2 += part[b * 128 + 64 + c];
    }
    __shared__ float ls[4][64], ls2[4][64];
    ls[g][c] = s; ls2[g][c] = s2;
    __syncthreads();
    if (tid < 64) {
        float t = 0.f, t2 = 0.f;
#pragma unroll
        for (int g2 = 0; g2 < 4; ++g2) { t += ls[g2][tid]; t2 += ls2[g2][tid]; }
        float mean = t * (1.0f / R_);
        float var  = t2 * (1.0f / R_) - mean * mean;
        float a = rsqrtf(var + 1e-5f) * gamma[tid];
        stats[tid]      = a;
        stats[64 + tid] = beta[tid] - mean * a;
    }
}

// ---------------------------------------------------------------------------
// bn_out: out[r][o] = sum_c relu(v[r][c]*a[c]+sh[c]) * w2[o][c] + b2[o]
// ---------------------------------------------------------------------------
__global__ __launch_bounds__(256) void bn_out(
    const float* __restrict__ Yh, const float* __restrict__ stats,
    const float* __restrict__ w2, const float* __restrict__ b2,
    float* __restrict__ out)
{
    __shared__ float ys[64 * 68];
    __shared__ float w2s[64 * 65];
    __shared__ float sa[64], sh[64];
    const int tid = threadIdx.x;
    const int r0 = blockIdx.x * 64;
#pragma unroll
    for (int i = 0; i < 16; ++i) {
        int idx = tid + i * 256;
        w2s[(idx >> 6) * 65 + (idx & 63)] = w2[idx];
    }
    if (tid < 64) { sa[tid] = stats[tid]; sh[tid] = stats[64 + tid]; }
    __syncthreads();
    const int o = tid & 63, g = tid >> 6;
    {
        float a = sa[o], b = sh[o];
#pragma unroll
        for (int p = 0; p < 16; ++p) {
            int rl = p * 4 + g;
            size_t off = (size_t)(r0 + rl) * 64 + o;
            float v = Yh[off] + Yh[(size_t)R_ * 64 + off];
            ys[o * 68 + rl] = fmaxf(fmaf(v, a, b), 0.f);
        }
    }
    __syncthreads();
    float acc[16];
    float bb = b2[o];
#pragma unroll
    for (int j = 0; j < 16; ++j) acc[j] = bb;
    for (int c = 0; c < 64; ++c) {
        float wv = w2s[o * 65 + c];
        const float* yr = ys + c * 68 + g * 16;
        f32x4 y0 = *(const f32x4*)(yr);
        f32x4 y1 = *(const f32x4*)(yr + 4);
        f32x4 y2 = *(const f32x4*)(yr + 8);
        f32x4 y3 = *(const f32x4*)(yr + 12);
#pragma unroll
        for (int j = 0; j < 4; ++j) {
            acc[j]      = fmaf(wv, y0[j], acc[j]);
            acc[4 + j]  = fmaf(wv, y1[j], acc[4 + j]);
            acc[8 + j]  = fmaf(wv, y2[j], acc[8 + j]);
            acc[12 + j] = fmaf(wv, y3[j], acc[12 + j]);
        }
    }
#pragma unroll
    for (int j = 0; j < 16; ++j)
        out[(size_t)(r0 + g * 16 + j) * OUT_ + o] = acc[j];
}

// ---------------------------------------------------------------------------
extern "C" void kernel_launch(void* const* d_in, const int* in_sizes, int n_in,
                              void* d_out, int out_size, void* d_ws, size_t ws_size,
                              hipStream_t stream)
{
    const float* x       = (const float*)d_in[0];
    const float* support = (const float*)d_in[1];
    const float* weight  = (const float*)d_in[2];
    const float* eps     = (const float*)d_in[3];
    const float* gamma   = (const float*)d_in[4];
    const float* beta    = (const float*)d_in[5];
    const float* w2      = (const float*)d_in[6];
    const float* b2      = (const float*)d_in[7];
    float* out = (float*)d_out;

    char* ws = (char*)d_ws;
    u16*   xb    = (u16*)(ws);                      // 25,165,824
    u16*   MallC = (u16*)(ws + 25165824);           //  2,097,152  [512][2048]
    u16*   MT    = (u16*)(ws + 27262976);           //  1,048,576
    u16*   Wt    = (u16*)(ws + 28311552);           //    393,216  [256][768]
    u16*   Z     = (u16*)(ws + 28704768);           //  8,388,608  [2048][2048]
    float* Yh    = (float*)(ws + 37093376);         //  8,388,608  (2 halves)
    float* part  = (float*)(ws + 45481984);         //    131,072
    float* stats = (float*)(ws + 45613056);         //        512

    prep3   <<<7424, 256, 0, stream>>>(x, support, weight, eps, xb, MallC, MT, Wt);
    zmsq    <<<544,  256, 0, stream>>>(Wt, xb, MallC, MT, Z, MallC);
    ysum    <<<512,  256, 0, stream>>>(MallC, Z, Yh);
    bn_part <<<256,  256, 0, stream>>>(Yh, part);
    bn_final<<<1,    256, 0, stream>>>(part, gamma, beta, stats);
    bn_out  <<<256,  256, 0, stream>>>(Yh, stats, w2, b2, out);
}